// Round 9
// baseline (182.399 us; speedup 1.0000x reference)
//
#include <hip/hip_runtime.h>
#include <cstdint>
#include <cstddef>

// Problem constants (from reference)
constexpr int BB   = 2;
constexpr int NN   = 8192;
constexpr int MM   = 8192;
constexpr int CIN  = 32;
constexpr int COUT = 32;
constexpr int EE   = 16;
constexpr int KK   = 32;
constexpr int GRID = 32;              // binning grid (h = 1/32, ~8 pts/cell)
constexpr int NCELL = GRID * GRID;

#define QPB 8          // queries per block (256 threads, 32 lanes/query)
#define CAP 128
#define SLOT_BYTES 2320   // >= max(KEY 1024 B, TL 2304 B); phases ordered per half-wave

// Workspace layout (bytes)
constexpr size_t OFS_COEFFT = 0;        // 16384 f = 65536 B
constexpr size_t OFS_COUNTS = 65536;    // 2*1024 i = 8192 B
constexpr size_t OFS_CURSOR = 73728;    // 2*1024 i = 8192 B
constexpr size_t OFS_STARTS = 81920;    // 2*1025 i = 8200 B (pad to 8704)
constexpr size_t OFS_PTSS   = 90624;    // 2*8192 float2 = 131072 B
constexpr size_t OFS_IDXS   = 221696;   // 2*8192 i = 65536 B  (total 287232 B)

// ---- coeff [CIN][COUT][E] -> coeffT [E][COUT][CIN] ------------------------------
__global__ __launch_bounds__(256) void transpose_coeff(const float* __restrict__ coeff,
                                                       float* __restrict__ coeffT) {
    int tid = blockIdx.x * 256 + threadIdx.x;
    if (tid >= EE * COUT * CIN) return;
    int i = tid & 31;
    int o = (tid >> 5) & 31;
    int e = tid >> 10;
    coeffT[tid] = coeff[(i * COUT + o) * EE + e];
}

// ---- binning: zero, count, scan, scatter ----------------------------------------
__global__ __launch_bounds__(256) void bin_zero(int* __restrict__ p) {
    int t = blockIdx.x * 256 + threadIdx.x;
    if (t < 2 * 2 * NCELL) p[t] = 0;
}

__device__ __forceinline__ int cell_of(float2 p) {
    int cx = min(GRID - 1, max(0, (int)(p.x * (float)GRID)));
    int cy = min(GRID - 1, max(0, (int)(p.y * (float)GRID)));
    return cy * GRID + cx;
}

__global__ __launch_bounds__(256) void bin_count(const float* __restrict__ pts,
                                                 int* __restrict__ counts) {
    int t = blockIdx.x * 256 + threadIdx.x;
    int b = t >> 13, i = t & (NN - 1);
    float2 p = ((const float2*)pts)[(size_t)b * NN + i];
    atomicAdd(&counts[b * NCELL + cell_of(p)], 1);
}

__global__ __launch_bounds__(1024) void bin_scan(const int* __restrict__ counts,
                                                 int* __restrict__ starts) {
    __shared__ int sm[NCELL];
    const int t = threadIdx.x;
    for (int b = 0; b < BB; ++b) {
        sm[t] = counts[b * NCELL + t];
        __syncthreads();
        for (int off = 1; off < NCELL; off <<= 1) {
            int v = (t >= off) ? sm[t - off] : 0;
            __syncthreads();
            sm[t] += v;
            __syncthreads();
        }
        starts[b * (NCELL + 1) + t + 1] = sm[t];
        if (t == 0) starts[b * (NCELL + 1)] = 0;
        __syncthreads();
    }
}

__global__ __launch_bounds__(256) void bin_scatter(const float* __restrict__ pts,
                                                   const int* __restrict__ starts,
                                                   int* __restrict__ cursor,
                                                   float2* __restrict__ pts_s,
                                                   int* __restrict__ idx_s) {
    int t = blockIdx.x * 256 + threadIdx.x;
    int b = t >> 13, i = t & (NN - 1);
    float2 p = ((const float2*)pts)[(size_t)b * NN + i];
    int cell = cell_of(p);
    int pos = starts[b * (NCELL + 1) + cell] + atomicAdd(&cursor[b * NCELL + cell], 1);
    pts_s[(size_t)b * NN + pos] = p;     // intra-cell order nondeterministic; final
    idx_s[(size_t)b * NN + pos] = i;     // rank by (d, orig idx) makes output exact.
}

// ---- main query kernel: one HALF-WAVE (32 lanes) per output point ---------------
__global__ __launch_bounds__(256, 6) void conv_query(
    const float2* __restrict__ pts_s, const int* __restrict__ idx_s,
    const int* __restrict__ starts,
    const float* __restrict__ points_in, const float* __restrict__ values_in,
    const float* __restrict__ points_out,
    const float* __restrict__ coeffT, const float* __restrict__ bias,
    float* __restrict__ out_uiv, float* __restrict__ out_idx,
    float* __restrict__ out_val)
{
    // KEY (select phase) and TL (einsum phase) are per-qslot, phase-ordered
    // within the owning half-wave -> union them; 8*2320 = 18.6 KB/block.
    __shared__ alignas(16) unsigned char SMEM[QPB][SLOT_BYTES];

    const int tid   = threadIdx.x;
    const int sl    = tid & 31;            // sub-lane within the query's half-wave
    const int qslot = tid >> 5;            // 0..7
    const int half  = qslot & 1;           // which half of the wave
    const int wid   = blockIdx.x * QPB + qslot;
    const int b     = wid >> 13;
    const int m     = wid & (MM - 1);

    unsigned long long* KEYq = (unsigned long long*)&SMEM[qslot][0];
    float*              TLq  = (float*)&SMEM[qslot][0];   // [16][36] padded

    const float2* PS = pts_s + (size_t)b * NN;
    const int*    IS = idx_s + (size_t)b * NN;
    const int*    ST = starts + b * (NCELL + 1);
    const float2* P  = ((const float2*)points_in) + (size_t)b * NN;
    const float2  q  = ((const float2*)points_out)[(size_t)b * MM + m];

    const float INF = __builtin_inff();
    const float h = 1.0f / (float)GRID;
    const int cx = min(GRID - 1, max(0, (int)(q.x * (float)GRID)));
    const int cy = min(GRID - 1, max(0, (int)(q.y * (float)GRID)));
    const unsigned lmlt32 = (1u << sl) - 1u;

    float bd;   // sorted exact distance (sub-lane sl holds entry #sl)
    int   bi;   // sorted original index
    int L = 2;

    for (;;) {
        const int xlo = max(cx - L, 0), xhi = min(cx + L, GRID - 1);
        const int ylo = max(cy - L, 0), yhi = min(cy + L, GRID - 1);
        const int nrows = yhi - ylo + 1;          // <= 32

        int sv = 0, ev = 0;
        if (sl < nrows) {
            sv = ST[(ylo + sl) * GRID + xlo];
            ev = ST[(ylo + sl) * GRID + xhi + 1];
        }

        // ---- pass 1: per-lane min1/min2 of d^2 over candidates ----
        float mn1 = INF, mn2 = INF;
        for (int r = 0; r < nrows; ++r) {
            const int s = __shfl(sv, r, 32), e = __shfl(ev, r, 32);
            for (int j = s + sl; j < e; j += 32) {
                const float2 p = PS[j];
                const float dx = q.x - p.x, dy = q.y - p.y;
                const float d2 = __builtin_fmaf(dy, dy, __fmul_rn(dx, dx));
                const float big = fmaxf(mn1, d2);
                mn1 = fminf(mn1, d2);
                mn2 = fminf(mn2, big);
            }
        }

        // ---- tau^2 = 16th smallest of the 32 lane-min2 (bitonic-32) ----
        // <=31 cands strictly < d2_(32) => <=15 lanes hold >=2 such cands
        // => at most 15 lane-min2 strictly below => 16th smallest >= d2_(32).
        {
            float v = mn2;
#pragma unroll
            for (int k = 2; k <= 32; k <<= 1) {
#pragma unroll
                for (int j = k >> 1; j > 0; j >>= 1) {
                    const float o = __shfl_xor(v, j, 32);
                    const bool up = ((sl & k) == 0), lower = ((sl & j) == 0);
                    const float mnv = fminf(v, o), mxv = fmaxf(v, o);
                    v = (lower == up) ? mnv : mxv;
                }
            }
            mn2 = __shfl(v, 15, 32);
        }
        const float tau2b = mn2 * (1.0f + 4e-6f);

        // ---- pass 2: compact survivors (exact numpy-semantics distance) ----
        int base = 0;
        for (int r = 0; r < nrows; ++r) {
            const int s = __shfl(sv, r, 32), e = __shfl(ev, r, 32);
            for (int j0 = s; j0 < e; j0 += 32) {
                const int j = j0 + sl;
                const bool valid = (j < e);
                float2 p = make_float2(0.f, 0.f);
                if (valid) p = PS[j];
                const float dx = q.x - p.x, dy = q.y - p.y;
                const float d2 = __builtin_fmaf(dy, dy, __fmul_rn(dx, dx));
                const bool pred = valid && (d2 <= tau2b);
                const unsigned bm = (unsigned)(__ballot(pred) >> (half << 5));
                if (bm) {
                    const float ex = __fsqrt_rn(__fadd_rn(__fmul_rn(dx, dx),
                                                          __fmul_rn(dy, dy)));
                    const int pos = base + __popc(bm & lmlt32);
                    if (pred && pos < CAP)
                        KEYq[pos] =
                            ((unsigned long long)__float_as_uint(ex) << 32) | (unsigned)IS[j];
                    base += __popc(bm);
                }
            }
        }

        if (base <= CAP) {
            // ---- rank-select: exact sorted top-32 without sorting ----
            // Keys are DISTINCT (unique idx low word) -> rank = #{keys < mine}
            // is a bijection onto 0..base-1. Broadcast-read loop has no
            // dependent chain; lanes with rank<32 scatter into KEYq[rank].
            // Same-wave LDS program order guarantees reads-before-writes.
            unsigned long long k0 = (sl      < base) ? KEYq[sl]      : ~0ull;
            unsigned long long k1 = (sl + 32 < base) ? KEYq[sl + 32] : ~0ull;
            int r0 = 0, r1 = 0;
            if (!__any(base > 64)) {
                for (int t = 0; t < base; ++t) {
                    const unsigned long long kt = KEYq[t];
                    r0 += (kt < k0) ? 1 : 0;
                    r1 += (kt < k1) ? 1 : 0;
                }
            } else {
                unsigned long long k2 = (sl + 64 < base) ? KEYq[sl + 64] : ~0ull;
                unsigned long long k3 = (sl + 96 < base) ? KEYq[sl + 96] : ~0ull;
                int r2 = 0, r3 = 0;
                for (int t = 0; t < base; ++t) {
                    const unsigned long long kt = KEYq[t];
                    r0 += (kt < k0) ? 1 : 0;
                    r1 += (kt < k1) ? 1 : 0;
                    r2 += (kt < k2) ? 1 : 0;
                    r3 += (kt < k3) ? 1 : 0;
                }
                if (sl + 64 < base && r2 < 32) KEYq[r2] = k2;
                if (sl + 96 < base && r3 < 32) KEYq[r3] = k3;
            }
            if (sl      < base && r0 < 32) KEYq[r0] = k0;
            if (sl + 32 < base && r1 < 32) KEYq[r1] = k1;
            if (base < 32 && sl >= base) KEYq[sl] = ~0ull;   // pad -> NaN -> expand
            const unsigned long long kf = KEYq[sl];
            bd = __uint_as_float((unsigned)(kf >> 32));
            bi = (int)(unsigned)(kf & 0xffffffffull);
        } else {
            // overflow fallback (astronomically rare): full rescan, serial insertion
            float fd = INF; int fi = 0x7FFFFFFF;
            for (int r = 0; r < nrows; ++r) {
                const int s = __shfl(sv, r, 32), e = __shfl(ev, r, 32);
                for (int j0 = s; j0 < e; j0 += 32) {
                    const int j = j0 + sl;
                    const bool valid = (j < e);
                    float2 p = make_float2(0.f, 0.f);
                    int vi0 = 0x7FFFFFFF;
                    if (valid) { p = PS[j]; vi0 = IS[j]; }
                    const float dx = q.x - p.x, dy = q.y - p.y;
                    const float d2 = __builtin_fmaf(dy, dy, __fmul_rn(dx, dx));
                    unsigned cm = (unsigned)(__ballot(valid && (d2 <= tau2b)) >> (half << 5));
                    const float ex = __fsqrt_rn(__fadd_rn(__fmul_rn(dx, dx),
                                                          __fmul_rn(dy, dy)));
                    while (cm) {
                        const int l = __builtin_ctz(cm); cm &= cm - 1;
                        const float v  = __shfl(ex, l, 32);
                        const int   vi = __shfl(vi0, l, 32);
                        const bool cl = (fd < v) || (fd == v && fi < vi);
                        const int pos = __popc((unsigned)(__ballot(cl) >> (half << 5)));
                        const float sd = __shfl_up(fd, 1, 32);
                        const int   si = __shfl_up(fi, 1, 32);
                        fd = (sl < pos) ? fd : ((sl == pos) ? v  : sd);
                        fi = (sl < pos) ? fi : ((sl == pos) ? vi : si);
                    }
                }
            }
            bd = fd; bi = fi;
        }

        // ---- exactness check: 32nd distance must beat the unexamined region ----
        const float tau = __shfl(bd, 31, 32);      // NaN if < 32 candidates
        float g = INF;
        if (xlo > 0)        g = fminf(g, q.x - (float)xlo * h);
        if (xhi < GRID - 1) g = fminf(g, (float)(xhi + 1) * h - q.x);
        if (ylo > 0)        g = fminf(g, q.y - (float)ylo * h);
        if (yhi < GRID - 1) g = fminf(g, (float)(yhi + 1) * h - q.y);
        if (tau < g * (1.0f - 4e-6f)) break;       // NaN -> expand
        L += 2;
        if (L > GRID - 1) L = GRID - 1;            // full box => g = INF => terminate
    }

    __builtin_amdgcn_sched_barrier(0);   // contain live ranges at phase boundary

    // ---- outputs 0 and 1: uiv_k and idx (as float) ----
    {
        const float2 pk = P[bi];
        float2 u;
        u.x = q.x - pk.x;
        u.y = q.y - pk.y;
        ((float2*)out_uiv)[(size_t)wid * KK + sl] = u;
        out_idx[(size_t)wid * KK + sl] = (float)bi;
    }

    __builtin_amdgcn_sched_barrier(0);

    // ---- T[e][i] = sum_k exp(-256*(r_k - mu_e)^2) * values_in[b, idx_k, i] ----
    // lane = (e-pair, i-quarter): 2 float4 loads per k (32B).
    // TLq is written and read by this same half-wave only -> no barrier needed.
    {
        const int e2 = sl >> 2;                 // 0..7 -> e in {2*e2, 2*e2+1}
        const int iq = sl & 3;                  // i-block of 8
        const float mu0 = (float)(2 * e2)     * (1.0f / 15.0f);
        const float mu1 = (float)(2 * e2 + 1) * (1.0f / 15.0f);
        float4 A0a = make_float4(0.f, 0.f, 0.f, 0.f);
        float4 A0b = A0a, A1a = A0a, A1b = A0a;
#pragma unroll
        for (int k = 0; k < KK; ++k) {
            const float rk  = __shfl(bd, k, 32);
            const int   bik = __shfl(bi, k, 32);
            const float d0 = rk - mu0;
            const float d1 = rk - mu1;
            const float w0 = __expf(-256.0f * d0 * d0);
            const float w1 = __expf(-256.0f * d1 * d1);
            const float4* vr = (const float4*)(values_in + ((size_t)b * NN + bik) * CIN + iq * 8);
            const float4 va = vr[0], vb = vr[1];
            A0a.x += w0 * va.x; A0a.y += w0 * va.y; A0a.z += w0 * va.z; A0a.w += w0 * va.w;
            A0b.x += w0 * vb.x; A0b.y += w0 * vb.y; A0b.z += w0 * vb.z; A0b.w += w0 * vb.w;
            A1a.x += w1 * va.x; A1a.y += w1 * va.y; A1a.z += w1 * va.z; A1a.w += w1 * va.w;
            A1b.x += w1 * vb.x; A1b.y += w1 * vb.y; A1b.z += w1 * vb.z; A1b.w += w1 * vb.w;
        }
        float4* t0 = (float4*)(TLq + (2 * e2)     * 36 + iq * 8);
        float4* t1 = (float4*)(TLq + (2 * e2 + 1) * 36 + iq * 8);
        t0[0] = A0a; t0[1] = A0b;
        t1[0] = A1a; t1[1] = A1b;
    }

    __builtin_amdgcn_sched_barrier(0);

    // ---- out[o] = (1/K) * sum_{e,i} coeffT[e][o][i] * T[e][i] + bias[o] ----
    {
        const int o = sl;
        float s = 0.f;
#pragma unroll
        for (int e2 = 0; e2 < EE; ++e2) {
            const float4* crow = (const float4*)(coeffT + ((size_t)e2 * COUT + o) * CIN);
            const float4* trow = (const float4*)(TLq + e2 * 36);
#pragma unroll
            for (int i4 = 0; i4 < 8; ++i4) {
                const float4 c  = crow[i4];
                const float4 tv = trow[i4];
                s += c.x * tv.x + c.y * tv.y + c.z * tv.z + c.w * tv.w;
            }
        }
        out_val[(size_t)wid * COUT + o] = s * (1.0f / 32.0f) + bias[o];
    }
}

extern "C" void kernel_launch(void* const* d_in, const int* in_sizes, int n_in,
                              void* d_out, int out_size, void* d_ws, size_t ws_size,
                              hipStream_t stream) {
    const float* points_in  = (const float*)d_in[0];
    const float* values_in  = (const float*)d_in[1];
    const float* points_out = (const float*)d_in[2];
    const float* coeff      = (const float*)d_in[3];
    const float* bias       = (const float*)d_in[4];

    float* out     = (float*)d_out;
    float* out_uiv = out;                                        // B*M*K*2
    float* out_idx = out + (size_t)BB * MM * KK * 2;             // B*M*K
    float* out_val = out_idx + (size_t)BB * MM * KK;             // B*M*COUT

    char* ws = (char*)d_ws;
    float*  coeffT = (float*)(ws + OFS_COEFFT);
    int*    counts = (int*)  (ws + OFS_COUNTS);
    int*    cursor = (int*)  (ws + OFS_CURSOR);
    int*    strts  = (int*)  (ws + OFS_STARTS);
    float2* pts_s  = (float2*)(ws + OFS_PTSS);
    int*    idx_s  = (int*)  (ws + OFS_IDXS);

    hipLaunchKernelGGL(transpose_coeff, dim3(64), dim3(256), 0, stream, coeff, coeffT);
    hipLaunchKernelGGL(bin_zero, dim3(16), dim3(256), 0, stream, counts);
    hipLaunchKernelGGL(bin_count, dim3(64), dim3(256), 0, stream, points_in, counts);
    hipLaunchKernelGGL(bin_scan, dim3(1), dim3(1024), 0, stream, counts, strts);
    hipLaunchKernelGGL(bin_scatter, dim3(64), dim3(256), 0, stream,
                       points_in, strts, cursor, pts_s, idx_s);

    const int blocks = (BB * MM) / QPB;                          // 2048
    hipLaunchKernelGGL(conv_query, dim3(blocks), dim3(256), 0, stream,
                       pts_s, idx_s, strts, points_in, values_in, points_out,
                       coeffT, bias, out_uiv, out_idx, out_val);
}

// Round 10
// 162.677 us; speedup vs baseline: 1.1212x; 1.1212x over previous
//
#include <hip/hip_runtime.h>
#include <cstdint>
#include <cstddef>

// Problem constants (from reference)
constexpr int BB   = 2;
constexpr int NN   = 8192;
constexpr int MM   = 8192;
constexpr int CIN  = 32;
constexpr int COUT = 32;
constexpr int EE   = 16;
constexpr int KK   = 32;
constexpr int GRID = 32;              // binning grid (h = 1/32, ~8 pts/cell)
constexpr int NCELL = GRID * GRID;

#define QPB 8          // queries per block (256 threads, 32 lanes/query)
#define CAP 128
#define SLOT_BYTES 2320   // >= max(KEY 1024 B, TL 2304 B); phases ordered per half-wave

// Workspace layout (bytes)
constexpr size_t OFS_COEFFT = 0;        // 16384 f = 65536 B
constexpr size_t OFS_COUNTS = 65536;    // 2*1024 i = 8192 B
constexpr size_t OFS_CURSOR = 73728;    // 2*1024 i = 8192 B
constexpr size_t OFS_STARTS = 81920;    // 2*1025 i = 8200 B (pad to 8704)
constexpr size_t OFS_PTSS   = 90624;    // 2*8192 float2 = 131072 B
constexpr size_t OFS_IDXS   = 221696;   // 2*8192 i = 65536 B  (total 287232 B)

// ---- coeff [CIN][COUT][E] -> coeffT [E][COUT][CIN] ------------------------------
__global__ __launch_bounds__(256) void transpose_coeff(const float* __restrict__ coeff,
                                                       float* __restrict__ coeffT) {
    int tid = blockIdx.x * 256 + threadIdx.x;
    if (tid >= EE * COUT * CIN) return;
    int i = tid & 31;
    int o = (tid >> 5) & 31;
    int e = tid >> 10;
    coeffT[tid] = coeff[(i * COUT + o) * EE + e];
}

// ---- binning: zero, count, scan, scatter ----------------------------------------
__global__ __launch_bounds__(256) void bin_zero(int* __restrict__ p) {
    int t = blockIdx.x * 256 + threadIdx.x;
    if (t < 2 * 2 * NCELL) p[t] = 0;
}

__device__ __forceinline__ int cell_of(float2 p) {
    int cx = min(GRID - 1, max(0, (int)(p.x * (float)GRID)));
    int cy = min(GRID - 1, max(0, (int)(p.y * (float)GRID)));
    return cy * GRID + cx;
}

__global__ __launch_bounds__(256) void bin_count(const float* __restrict__ pts,
                                                 int* __restrict__ counts) {
    int t = blockIdx.x * 256 + threadIdx.x;
    int b = t >> 13, i = t & (NN - 1);
    float2 p = ((const float2*)pts)[(size_t)b * NN + i];
    atomicAdd(&counts[b * NCELL + cell_of(p)], 1);
}

__global__ __launch_bounds__(1024) void bin_scan(const int* __restrict__ counts,
                                                 int* __restrict__ starts) {
    __shared__ int sm[NCELL];
    const int t = threadIdx.x;
    for (int b = 0; b < BB; ++b) {
        sm[t] = counts[b * NCELL + t];
        __syncthreads();
        for (int off = 1; off < NCELL; off <<= 1) {
            int v = (t >= off) ? sm[t - off] : 0;
            __syncthreads();
            sm[t] += v;
            __syncthreads();
        }
        starts[b * (NCELL + 1) + t + 1] = sm[t];
        if (t == 0) starts[b * (NCELL + 1)] = 0;
        __syncthreads();
    }
}

__global__ __launch_bounds__(256) void bin_scatter(const float* __restrict__ pts,
                                                   const int* __restrict__ starts,
                                                   int* __restrict__ cursor,
                                                   float2* __restrict__ pts_s,
                                                   int* __restrict__ idx_s) {
    int t = blockIdx.x * 256 + threadIdx.x;
    int b = t >> 13, i = t & (NN - 1);
    float2 p = ((const float2*)pts)[(size_t)b * NN + i];
    int cell = cell_of(p);
    int pos = starts[b * (NCELL + 1) + cell] + atomicAdd(&cursor[b * NCELL + cell], 1);
    pts_s[(size_t)b * NN + pos] = p;     // intra-cell order nondeterministic; final
    idx_s[(size_t)b * NN + pos] = i;     // rank by (d, orig idx) makes output exact.
}

// ---- main query kernel: one HALF-WAVE (32 lanes) per output point ---------------
// NOTE: no second __launch_bounds__ arg. Forced caps (8 -> 32 VGPR, 6 -> 40 VGPR)
// both spilled to scratch (FETCH/WRITE x5-x10). Natural allocation is the win
// condition: if it lands <= 64 VGPR we get 8 waves/SIMD for free.
__global__ __launch_bounds__(256) void conv_query(
    const float2* __restrict__ pts_s, const int* __restrict__ idx_s,
    const int* __restrict__ starts,
    const float* __restrict__ points_in, const float* __restrict__ values_in,
    const float* __restrict__ points_out,
    const float* __restrict__ coeffT, const float* __restrict__ bias,
    float* __restrict__ out_uiv, float* __restrict__ out_idx,
    float* __restrict__ out_val)
{
    // KEY (select phase) and TL (einsum phase) are per-qslot, phase-ordered
    // within the owning half-wave -> union them; 8*2320 = 18.6 KB/block.
    __shared__ alignas(16) unsigned char SMEM[QPB][SLOT_BYTES];

    const int tid   = threadIdx.x;
    const int sl    = tid & 31;            // sub-lane within the query's half-wave
    const int qslot = tid >> 5;            // 0..7
    const int half  = qslot & 1;           // which half of the wave
    const int wid   = blockIdx.x * QPB + qslot;
    const int b     = wid >> 13;
    const int m     = wid & (MM - 1);

    unsigned long long* KEYq = (unsigned long long*)&SMEM[qslot][0];
    float*              TLq  = (float*)&SMEM[qslot][0];   // [16][36] padded

    const float2* PS = pts_s + (size_t)b * NN;
    const int*    IS = idx_s + (size_t)b * NN;
    const int*    ST = starts + b * (NCELL + 1);
    const float2* P  = ((const float2*)points_in) + (size_t)b * NN;
    const float2  q  = ((const float2*)points_out)[(size_t)b * MM + m];

    const float INF = __builtin_inff();
    const float h = 1.0f / (float)GRID;
    const int cx = min(GRID - 1, max(0, (int)(q.x * (float)GRID)));
    const int cy = min(GRID - 1, max(0, (int)(q.y * (float)GRID)));
    const unsigned lmlt32 = (1u << sl) - 1u;

    float bd;   // sorted exact distance (sub-lane sl holds entry #sl)
    int   bi;   // sorted original index
    int L = 2;

    for (;;) {
        const int xlo = max(cx - L, 0), xhi = min(cx + L, GRID - 1);
        const int ylo = max(cy - L, 0), yhi = min(cy + L, GRID - 1);
        const int nrows = yhi - ylo + 1;          // <= 32

        int sv = 0, ev = 0;
        if (sl < nrows) {
            sv = ST[(ylo + sl) * GRID + xlo];
            ev = ST[(ylo + sl) * GRID + xhi + 1];
        }

        // ---- pass 1: per-lane min1/min2 of d^2 over candidates ----
        float mn1 = INF, mn2 = INF;
        for (int r = 0; r < nrows; ++r) {
            const int s = __shfl(sv, r, 32), e = __shfl(ev, r, 32);
            for (int j = s + sl; j < e; j += 32) {
                const float2 p = PS[j];
                const float dx = q.x - p.x, dy = q.y - p.y;
                const float d2 = __builtin_fmaf(dy, dy, __fmul_rn(dx, dx));
                const float big = fmaxf(mn1, d2);
                mn1 = fminf(mn1, d2);
                mn2 = fminf(mn2, big);
            }
        }

        // ---- tau^2 = 16th smallest of the 32 lane-min2 (bitonic-32) ----
        // <=31 cands strictly < d2_(32) => <=15 lanes hold >=2 such cands
        // => at most 15 lane-min2 strictly below => 16th smallest >= d2_(32).
        {
            float v = mn2;
#pragma unroll
            for (int k = 2; k <= 32; k <<= 1) {
#pragma unroll
                for (int j = k >> 1; j > 0; j >>= 1) {
                    const float o = __shfl_xor(v, j, 32);
                    const bool up = ((sl & k) == 0), lower = ((sl & j) == 0);
                    const float mnv = fminf(v, o), mxv = fmaxf(v, o);
                    v = (lower == up) ? mnv : mxv;
                }
            }
            mn2 = __shfl(v, 15, 32);
        }
        const float tau2b = mn2 * (1.0f + 4e-6f);

        // ---- pass 2: compact survivors (exact numpy-semantics distance) ----
        int base = 0;
        for (int r = 0; r < nrows; ++r) {
            const int s = __shfl(sv, r, 32), e = __shfl(ev, r, 32);
            for (int j0 = s; j0 < e; j0 += 32) {
                const int j = j0 + sl;
                const bool valid = (j < e);
                float2 p = make_float2(0.f, 0.f);
                if (valid) p = PS[j];
                const float dx = q.x - p.x, dy = q.y - p.y;
                const float d2 = __builtin_fmaf(dy, dy, __fmul_rn(dx, dx));
                const bool pred = valid && (d2 <= tau2b);
                const unsigned bm = (unsigned)(__ballot(pred) >> (half << 5));
                if (bm) {
                    const float ex = __fsqrt_rn(__fadd_rn(__fmul_rn(dx, dx),
                                                          __fmul_rn(dy, dy)));
                    const int pos = base + __popc(bm & lmlt32);
                    if (pred && pos < CAP)
                        KEYq[pos] =
                            ((unsigned long long)__float_as_uint(ex) << 32) | (unsigned)IS[j];
                    base += __popc(bm);
                }
            }
        }

        if (base <= CAP) {
            // ---- rank-select: exact sorted top-32 without sorting ----
            // Keys are DISTINCT (unique idx low word) -> rank = #{keys < mine}
            // is a bijection onto 0..base-1. Broadcast-read loop has no
            // dependent chain; lanes with rank<32 scatter into KEYq[rank].
            // Same-wave LDS program order guarantees reads-before-writes.
            unsigned long long k0 = (sl      < base) ? KEYq[sl]      : ~0ull;
            unsigned long long k1 = (sl + 32 < base) ? KEYq[sl + 32] : ~0ull;
            int r0 = 0, r1 = 0;
            if (!__any(base > 64)) {
                for (int t = 0; t < base; ++t) {
                    const unsigned long long kt = KEYq[t];
                    r0 += (kt < k0) ? 1 : 0;
                    r1 += (kt < k1) ? 1 : 0;
                }
            } else {
                unsigned long long k2 = (sl + 64 < base) ? KEYq[sl + 64] : ~0ull;
                unsigned long long k3 = (sl + 96 < base) ? KEYq[sl + 96] : ~0ull;
                int r2 = 0, r3 = 0;
                for (int t = 0; t < base; ++t) {
                    const unsigned long long kt = KEYq[t];
                    r0 += (kt < k0) ? 1 : 0;
                    r1 += (kt < k1) ? 1 : 0;
                    r2 += (kt < k2) ? 1 : 0;
                    r3 += (kt < k3) ? 1 : 0;
                }
                if (sl + 64 < base && r2 < 32) KEYq[r2] = k2;
                if (sl + 96 < base && r3 < 32) KEYq[r3] = k3;
            }
            if (sl      < base && r0 < 32) KEYq[r0] = k0;
            if (sl + 32 < base && r1 < 32) KEYq[r1] = k1;
            if (base < 32 && sl >= base) KEYq[sl] = ~0ull;   // pad -> NaN -> expand
            const unsigned long long kf = KEYq[sl];
            bd = __uint_as_float((unsigned)(kf >> 32));
            bi = (int)(unsigned)(kf & 0xffffffffull);
        } else {
            // overflow fallback (astronomically rare): full rescan, serial insertion
            float fd = INF; int fi = 0x7FFFFFFF;
            for (int r = 0; r < nrows; ++r) {
                const int s = __shfl(sv, r, 32), e = __shfl(ev, r, 32);
                for (int j0 = s; j0 < e; j0 += 32) {
                    const int j = j0 + sl;
                    const bool valid = (j < e);
                    float2 p = make_float2(0.f, 0.f);
                    int vi0 = 0x7FFFFFFF;
                    if (valid) { p = PS[j]; vi0 = IS[j]; }
                    const float dx = q.x - p.x, dy = q.y - p.y;
                    const float d2 = __builtin_fmaf(dy, dy, __fmul_rn(dx, dx));
                    unsigned cm = (unsigned)(__ballot(valid && (d2 <= tau2b)) >> (half << 5));
                    const float ex = __fsqrt_rn(__fadd_rn(__fmul_rn(dx, dx),
                                                          __fmul_rn(dy, dy)));
                    while (cm) {
                        const int l = __builtin_ctz(cm); cm &= cm - 1;
                        const float v  = __shfl(ex, l, 32);
                        const int   vi = __shfl(vi0, l, 32);
                        const bool cl = (fd < v) || (fd == v && fi < vi);
                        const int pos = __popc((unsigned)(__ballot(cl) >> (half << 5)));
                        const float sd = __shfl_up(fd, 1, 32);
                        const int   si = __shfl_up(fi, 1, 32);
                        fd = (sl < pos) ? fd : ((sl == pos) ? v  : sd);
                        fi = (sl < pos) ? fi : ((sl == pos) ? vi : si);
                    }
                }
            }
            bd = fd; bi = fi;
        }

        // ---- exactness check: 32nd distance must beat the unexamined region ----
        const float tau = __shfl(bd, 31, 32);      // NaN if < 32 candidates
        float g = INF;
        if (xlo > 0)        g = fminf(g, q.x - (float)xlo * h);
        if (xhi < GRID - 1) g = fminf(g, (float)(xhi + 1) * h - q.x);
        if (ylo > 0)        g = fminf(g, q.y - (float)ylo * h);
        if (yhi < GRID - 1) g = fminf(g, (float)(yhi + 1) * h - q.y);
        if (tau < g * (1.0f - 4e-6f)) break;       // NaN -> expand
        L += 2;
        if (L > GRID - 1) L = GRID - 1;            // full box => g = INF => terminate
    }

    __builtin_amdgcn_sched_barrier(0);   // contain live ranges at phase boundary

    // ---- outputs 0 and 1: uiv_k and idx (as float) ----
    {
        const float2 pk = P[bi];
        float2 u;
        u.x = q.x - pk.x;
        u.y = q.y - pk.y;
        ((float2*)out_uiv)[(size_t)wid * KK + sl] = u;
        out_idx[(size_t)wid * KK + sl] = (float)bi;
    }

    __builtin_amdgcn_sched_barrier(0);

    // ---- T[e][i] = sum_k exp(-256*(r_k - mu_e)^2) * values_in[b, idx_k, i] ----
    // lane = (e-pair, i-quarter): 2 float4 loads per k (32B).
    // TLq is written and read by this same half-wave only -> no barrier needed.
    {
        const int e2 = sl >> 2;                 // 0..7 -> e in {2*e2, 2*e2+1}
        const int iq = sl & 3;                  // i-block of 8
        const float mu0 = (float)(2 * e2)     * (1.0f / 15.0f);
        const float mu1 = (float)(2 * e2 + 1) * (1.0f / 15.0f);
        float4 A0a = make_float4(0.f, 0.f, 0.f, 0.f);
        float4 A0b = A0a, A1a = A0a, A1b = A0a;
#pragma unroll
        for (int k = 0; k < KK; ++k) {
            const float rk  = __shfl(bd, k, 32);
            const int   bik = __shfl(bi, k, 32);
            const float d0 = rk - mu0;
            const float d1 = rk - mu1;
            const float w0 = __expf(-256.0f * d0 * d0);
            const float w1 = __expf(-256.0f * d1 * d1);
            const float4* vr = (const float4*)(values_in + ((size_t)b * NN + bik) * CIN + iq * 8);
            const float4 va = vr[0], vb = vr[1];
            A0a.x += w0 * va.x; A0a.y += w0 * va.y; A0a.z += w0 * va.z; A0a.w += w0 * va.w;
            A0b.x += w0 * vb.x; A0b.y += w0 * vb.y; A0b.z += w0 * vb.z; A0b.w += w0 * vb.w;
            A1a.x += w1 * va.x; A1a.y += w1 * va.y; A1a.z += w1 * va.z; A1a.w += w1 * va.w;
            A1b.x += w1 * vb.x; A1b.y += w1 * vb.y; A1b.z += w1 * vb.z; A1b.w += w1 * vb.w;
        }
        float4* t0 = (float4*)(TLq + (2 * e2)     * 36 + iq * 8);
        float4* t1 = (float4*)(TLq + (2 * e2 + 1) * 36 + iq * 8);
        t0[0] = A0a; t0[1] = A0b;
        t1[0] = A1a; t1[1] = A1b;
    }

    __builtin_amdgcn_sched_barrier(0);

    // ---- out[o] = (1/K) * sum_{e,i} coeffT[e][o][i] * T[e][i] + bias[o] ----
    {
        const int o = sl;
        float s = 0.f;
#pragma unroll
        for (int e2 = 0; e2 < EE; ++e2) {
            const float4* crow = (const float4*)(coeffT + ((size_t)e2 * COUT + o) * CIN);
            const float4* trow = (const float4*)(TLq + e2 * 36);
#pragma unroll
            for (int i4 = 0; i4 < 8; ++i4) {
                const float4 c  = crow[i4];
                const float4 tv = trow[i4];
                s += c.x * tv.x + c.y * tv.y + c.z * tv.z + c.w * tv.w;
            }
        }
        out_val[(size_t)wid * COUT + o] = s * (1.0f / 32.0f) + bias[o];
    }
}

extern "C" void kernel_launch(void* const* d_in, const int* in_sizes, int n_in,
                              void* d_out, int out_size, void* d_ws, size_t ws_size,
                              hipStream_t stream) {
    const float* points_in  = (const float*)d_in[0];
    const float* values_in  = (const float*)d_in[1];
    const float* points_out = (const float*)d_in[2];
    const float* coeff      = (const float*)d_in[3];
    const float* bias       = (const float*)d_in[4];

    float* out     = (float*)d_out;
    float* out_uiv = out;                                        // B*M*K*2
    float* out_idx = out + (size_t)BB * MM * KK * 2;             // B*M*K
    float* out_val = out_idx + (size_t)BB * MM * KK;             // B*M*COUT

    char* ws = (char*)d_ws;
    float*  coeffT = (float*)(ws + OFS_COEFFT);
    int*    counts = (int*)  (ws + OFS_COUNTS);
    int*    cursor = (int*)  (ws + OFS_CURSOR);
    int*    strts  = (int*)  (ws + OFS_STARTS);
    float2* pts_s  = (float2*)(ws + OFS_PTSS);
    int*    idx_s  = (int*)  (ws + OFS_IDXS);

    hipLaunchKernelGGL(transpose_coeff, dim3(64), dim3(256), 0, stream, coeff, coeffT);
    hipLaunchKernelGGL(bin_zero, dim3(16), dim3(256), 0, stream, counts);
    hipLaunchKernelGGL(bin_count, dim3(64), dim3(256), 0, stream, points_in, counts);
    hipLaunchKernelGGL(bin_scan, dim3(1), dim3(1024), 0, stream, counts, strts);
    hipLaunchKernelGGL(bin_scatter, dim3(64), dim3(256), 0, stream,
                       points_in, strts, cursor, pts_s, idx_s);

    const int blocks = (BB * MM) / QPB;                          // 2048
    hipLaunchKernelGGL(conv_query, dim3(blocks), dim3(256), 0, stream,
                       pts_s, idx_s, strts, points_in, values_in, points_out,
                       coeffT, bias, out_uiv, out_idx, out_val);
}

// Round 11
// 158.524 us; speedup vs baseline: 1.1506x; 1.0262x over previous
//
#include <hip/hip_runtime.h>
#include <cstdint>
#include <cstddef>

// Problem constants (from reference)
constexpr int BB   = 2;
constexpr int NN   = 8192;
constexpr int MM   = 8192;
constexpr int CIN  = 32;
constexpr int COUT = 32;
constexpr int EE   = 16;
constexpr int KK   = 32;
constexpr int GRID = 32;              // binning grid (h = 1/32, ~8 pts/cell)
constexpr int NCELL = GRID * GRID;

#define QPB 8          // queries per block (256 threads, 32 lanes/query)
#define CAP 128
#define SLOT_BYTES 2320   // >= max(KEY 1024 B, TL 2304 B); phases ordered per half-wave

// Fixed-radius fast path: lambda = pi*R0^2*N ~ 58 expected candidates.
#define R0_FAST 0.0475f

// Workspace layout (bytes)
constexpr size_t OFS_COEFFT = 0;        // 16384 f = 65536 B
constexpr size_t OFS_COUNTS = 65536;    // 2*1024 i = 8192 B
constexpr size_t OFS_CURSOR = 73728;    // 2*1024 i = 8192 B
constexpr size_t OFS_STARTS = 81920;    // 2*1025 i = 8200 B (pad to 8704)
constexpr size_t OFS_PTSS   = 90624;    // 2*8192 float2 = 131072 B
constexpr size_t OFS_IDXS   = 221696;   // 2*8192 i = 65536 B  (total 287232 B)

// ---- coeff [CIN][COUT][E] -> coeffT [E][COUT][CIN] ------------------------------
__global__ __launch_bounds__(256) void transpose_coeff(const float* __restrict__ coeff,
                                                       float* __restrict__ coeffT) {
    int tid = blockIdx.x * 256 + threadIdx.x;
    if (tid >= EE * COUT * CIN) return;
    int i = tid & 31;
    int o = (tid >> 5) & 31;
    int e = tid >> 10;
    coeffT[tid] = coeff[(i * COUT + o) * EE + e];
}

// ---- binning: zero, count, scan, scatter ----------------------------------------
__global__ __launch_bounds__(256) void bin_zero(int* __restrict__ p) {
    int t = blockIdx.x * 256 + threadIdx.x;
    if (t < 2 * 2 * NCELL) p[t] = 0;
}

__device__ __forceinline__ int cell_of(float2 p) {
    int cx = min(GRID - 1, max(0, (int)(p.x * (float)GRID)));
    int cy = min(GRID - 1, max(0, (int)(p.y * (float)GRID)));
    return cy * GRID + cx;
}

__global__ __launch_bounds__(256) void bin_count(const float* __restrict__ pts,
                                                 int* __restrict__ counts) {
    int t = blockIdx.x * 256 + threadIdx.x;
    int b = t >> 13, i = t & (NN - 1);
    float2 p = ((const float2*)pts)[(size_t)b * NN + i];
    atomicAdd(&counts[b * NCELL + cell_of(p)], 1);
}

__global__ __launch_bounds__(1024) void bin_scan(const int* __restrict__ counts,
                                                 int* __restrict__ starts) {
    __shared__ int sm[NCELL];
    const int t = threadIdx.x;
    for (int b = 0; b < BB; ++b) {
        sm[t] = counts[b * NCELL + t];
        __syncthreads();
        for (int off = 1; off < NCELL; off <<= 1) {
            int v = (t >= off) ? sm[t - off] : 0;
            __syncthreads();
            sm[t] += v;
            __syncthreads();
        }
        starts[b * (NCELL + 1) + t + 1] = sm[t];
        if (t == 0) starts[b * (NCELL + 1)] = 0;
        __syncthreads();
    }
}

__global__ __launch_bounds__(256) void bin_scatter(const float* __restrict__ pts,
                                                   const int* __restrict__ starts,
                                                   int* __restrict__ cursor,
                                                   float2* __restrict__ pts_s,
                                                   int* __restrict__ idx_s) {
    int t = blockIdx.x * 256 + threadIdx.x;
    int b = t >> 13, i = t & (NN - 1);
    float2 p = ((const float2*)pts)[(size_t)b * NN + i];
    int cell = cell_of(p);
    int pos = starts[b * (NCELL + 1) + cell] + atomicAdd(&cursor[b * NCELL + cell], 1);
    pts_s[(size_t)b * NN + pos] = p;     // intra-cell order nondeterministic; final
    idx_s[(size_t)b * NN + pos] = i;     // rank by (d, orig idx) makes output exact.
}

// ---- main query kernel: one HALF-WAVE (32 lanes) per output point ---------------
__global__ __launch_bounds__(256) void conv_query(
    const float2* __restrict__ pts_s, const int* __restrict__ idx_s,
    const int* __restrict__ starts,
    const float* __restrict__ points_in, const float* __restrict__ values_in,
    const float* __restrict__ points_out,
    const float* __restrict__ coeffT, const float* __restrict__ bias,
    float* __restrict__ out_uiv, float* __restrict__ out_idx,
    float* __restrict__ out_val)
{
    __shared__ alignas(16) unsigned char SMEM[QPB][SLOT_BYTES];

    const int tid   = threadIdx.x;
    const int sl    = tid & 31;            // sub-lane within the query's half-wave
    const int qslot = tid >> 5;            // 0..7
    const int half  = qslot & 1;           // which half of the wave
    const int wid   = blockIdx.x * QPB + qslot;
    const int b     = wid >> 13;
    const int m     = wid & (MM - 1);

    unsigned long long* KEYq = (unsigned long long*)&SMEM[qslot][0];
    float*              TLq  = (float*)&SMEM[qslot][0];   // [16][36] padded

    const float2* PS = pts_s + (size_t)b * NN;
    const int*    IS = idx_s + (size_t)b * NN;
    const int*    ST = starts + b * (NCELL + 1);
    const float2* P  = ((const float2*)points_in) + (size_t)b * NN;
    const float2  q  = ((const float2*)points_out)[(size_t)b * MM + m];

    const float INF = __builtin_inff();
    const float h = 1.0f / (float)GRID;
    const unsigned lmlt32 = (1u << sl) - 1u;

    float bd;   // sorted exact distance (sub-lane sl holds entry #sl)
    int   bi;   // sorted original index
    bool  ok = false;

    // ================= FAST PATH: fixed analytic radius, single scan ==============
    {
        // edge/corner-corrected radius so that expected candidates ~ lambda=58
        float tau = R0_FAST;
        {
            const float bx = fminf(q.x, 1.0f - q.x);
            const float by = fminf(q.y, 1.0f - q.y);
#pragma unroll
            for (int it = 0; it < 3; ++it) {
                const float wx = 0.5f + 0.5f * fminf(bx / tau, 1.0f);
                const float wy = 0.5f + 0.5f * fminf(by / tau, 1.0f);
                tau = R0_FAST * __frsqrt_rn(wx * wy);
            }
        }
        const float tau2  = tau * tau;             // strict (sufficiency) threshold
        const float tau2a = tau2 * (1.0f + 2e-6f); // admit threshold (covers rounding)

        const int xlo = (int)fmaxf((q.x - tau) * (float)GRID, 0.0f);
        const int xhi = (int)fminf((q.x + tau) * (float)GRID, (float)(GRID - 1));
        const int ylo = (int)fmaxf((q.y - tau) * (float)GRID, 0.0f);
        const int yhi = (int)fminf((q.y + tau) * (float)GRID, (float)(GRID - 1));
        const int nrows = yhi - ylo + 1;

        int sv = 0, ev = 0;
        if (sl < nrows) {
            sv = ST[(ylo + sl) * GRID + xlo];
            ev = ST[(ylo + sl) * GRID + xhi + 1];
        }

        // single scan: compute d2, count strict, compact admitted with exact key
        int base = 0, nin = 0;
        for (int r = 0; r < nrows; ++r) {
            const int s = __shfl(sv, r, 32), e = __shfl(ev, r, 32);
            for (int j0 = s; j0 < e; j0 += 32) {
                const int j = j0 + sl;
                const bool valid = (j < e);
                float2 p = make_float2(2.0f, 2.0f);
                if (valid) p = PS[j];
                const float dx = q.x - p.x, dy = q.y - p.y;
                const float d2 = __builtin_fmaf(dy, dy, __fmul_rn(dx, dx));
                const bool adm = valid && (d2 <= tau2a);
                const unsigned bmA = (unsigned)(__ballot(adm) >> (half << 5));
                const unsigned bmS = (unsigned)(__ballot(valid && (d2 <= tau2)) >> (half << 5));
                nin += __popc(bmS);
                if (bmA) {
                    const float ex = __fsqrt_rn(__fadd_rn(__fmul_rn(dx, dx),
                                                          __fmul_rn(dy, dy)));
                    const int pos = base + __popc(bmA & lmlt32);
                    if (adm && pos < CAP)
                        KEYq[pos] =
                            ((unsigned long long)__float_as_uint(ex) << 32) | (unsigned)IS[j];
                    base += __popc(bmA);
                }
            }
        }

        // sufficiency: >=32 strictly-inside => exact top-32 subset of admitted
        ok = (nin >= 32) && (base <= CAP);
        if (ok) {
            // rank-select: exact sorted top-32 (keys distinct via unique idx)
            unsigned long long k0 = (sl      < base) ? KEYq[sl]      : ~0ull;
            unsigned long long k1 = (sl + 32 < base) ? KEYq[sl + 32] : ~0ull;
            int r0 = 0, r1 = 0;
            if (!__any(base > 64)) {
                for (int t = 0; t < base; ++t) {
                    const unsigned long long kt = KEYq[t];
                    r0 += (kt < k0) ? 1 : 0;
                    r1 += (kt < k1) ? 1 : 0;
                }
            } else {
                unsigned long long k2 = (sl + 64 < base) ? KEYq[sl + 64] : ~0ull;
                unsigned long long k3 = (sl + 96 < base) ? KEYq[sl + 96] : ~0ull;
                int r2 = 0, r3 = 0;
                for (int t = 0; t < base; ++t) {
                    const unsigned long long kt = KEYq[t];
                    r0 += (kt < k0) ? 1 : 0;
                    r1 += (kt < k1) ? 1 : 0;
                    r2 += (kt < k2) ? 1 : 0;
                    r3 += (kt < k3) ? 1 : 0;
                }
                if (sl + 64 < base && r2 < 32) KEYq[r2] = k2;
                if (sl + 96 < base && r3 < 32) KEYq[r3] = k3;
            }
            if (sl      < base && r0 < 32) KEYq[r0] = k0;
            if (sl + 32 < base && r1 < 32) KEYq[r1] = k1;
            const unsigned long long kf = KEYq[sl];
            bd = __uint_as_float((unsigned)(kf >> 32));
            bi = (int)(unsigned)(kf & 0xffffffffull);

            // g-check against the box ACTUALLY scanned (immune to box rounding):
            // every unexamined point is at distance >= g from q.
            const float tau32 = __shfl(bd, 31, 32);
            float g = INF;
            if (xlo > 0)        g = fminf(g, q.x - (float)xlo * h);
            if (xhi < GRID - 1) g = fminf(g, (float)(xhi + 1) * h - q.x);
            if (ylo > 0)        g = fminf(g, q.y - (float)ylo * h);
            if (yhi < GRID - 1) g = fminf(g, (float)(yhi + 1) * h - q.y);
            ok = (tau32 < g * (1.0f - 4e-6f));
        }
    }

    // ================= SLOW PATH (rare, ~2.5e-4/query): adaptive, exact ===========
    if (!ok) {
        const int cx = min(GRID - 1, max(0, (int)(q.x * (float)GRID)));
        const int cy = min(GRID - 1, max(0, (int)(q.y * (float)GRID)));
        int L = 2;
        for (;;) {
            const int xlo = max(cx - L, 0), xhi = min(cx + L, GRID - 1);
            const int ylo = max(cy - L, 0), yhi = min(cy + L, GRID - 1);
            const int nrows = yhi - ylo + 1;          // <= 32

            int sv = 0, ev = 0;
            if (sl < nrows) {
                sv = ST[(ylo + sl) * GRID + xlo];
                ev = ST[(ylo + sl) * GRID + xhi + 1];
            }

            // pass 1: per-lane min1/min2 of d^2
            float mn1 = INF, mn2 = INF;
            for (int r = 0; r < nrows; ++r) {
                const int s = __shfl(sv, r, 32), e = __shfl(ev, r, 32);
                for (int j = s + sl; j < e; j += 32) {
                    const float2 p = PS[j];
                    const float dx = q.x - p.x, dy = q.y - p.y;
                    const float d2 = __builtin_fmaf(dy, dy, __fmul_rn(dx, dx));
                    const float big = fmaxf(mn1, d2);
                    mn1 = fminf(mn1, d2);
                    mn2 = fminf(mn2, big);
                }
            }

            // tau^2 = 16th smallest of 32 lane-min2 (bitonic-32); upper bound proof:
            // <=31 cands strictly < d2_(32) => <=15 lane-min2 strictly below.
            {
                float v = mn2;
#pragma unroll
                for (int k = 2; k <= 32; k <<= 1) {
#pragma unroll
                    for (int j = k >> 1; j > 0; j >>= 1) {
                        const float o = __shfl_xor(v, j, 32);
                        const bool up = ((sl & k) == 0), lower = ((sl & j) == 0);
                        const float mnv = fminf(v, o), mxv = fmaxf(v, o);
                        v = (lower == up) ? mnv : mxv;
                    }
                }
                mn2 = __shfl(v, 15, 32);
            }
            const float tau2b = mn2 * (1.0f + 4e-6f);

            // pass 2: compact survivors with exact keys
            int base = 0;
            for (int r = 0; r < nrows; ++r) {
                const int s = __shfl(sv, r, 32), e = __shfl(ev, r, 32);
                for (int j0 = s; j0 < e; j0 += 32) {
                    const int j = j0 + sl;
                    const bool valid = (j < e);
                    float2 p = make_float2(0.f, 0.f);
                    if (valid) p = PS[j];
                    const float dx = q.x - p.x, dy = q.y - p.y;
                    const float d2 = __builtin_fmaf(dy, dy, __fmul_rn(dx, dx));
                    const bool pred = valid && (d2 <= tau2b);
                    const unsigned bm = (unsigned)(__ballot(pred) >> (half << 5));
                    if (bm) {
                        const float ex = __fsqrt_rn(__fadd_rn(__fmul_rn(dx, dx),
                                                              __fmul_rn(dy, dy)));
                        const int pos = base + __popc(bm & lmlt32);
                        if (pred && pos < CAP)
                            KEYq[pos] =
                                ((unsigned long long)__float_as_uint(ex) << 32) | (unsigned)IS[j];
                        base += __popc(bm);
                    }
                }
            }

            if (base <= CAP) {
                unsigned long long k0 = (sl      < base) ? KEYq[sl]      : ~0ull;
                unsigned long long k1 = (sl + 32 < base) ? KEYq[sl + 32] : ~0ull;
                int r0 = 0, r1 = 0;
                if (!__any(base > 64)) {
                    for (int t = 0; t < base; ++t) {
                        const unsigned long long kt = KEYq[t];
                        r0 += (kt < k0) ? 1 : 0;
                        r1 += (kt < k1) ? 1 : 0;
                    }
                } else {
                    unsigned long long k2 = (sl + 64 < base) ? KEYq[sl + 64] : ~0ull;
                    unsigned long long k3 = (sl + 96 < base) ? KEYq[sl + 96] : ~0ull;
                    int r2 = 0, r3 = 0;
                    for (int t = 0; t < base; ++t) {
                        const unsigned long long kt = KEYq[t];
                        r0 += (kt < k0) ? 1 : 0;
                        r1 += (kt < k1) ? 1 : 0;
                        r2 += (kt < k2) ? 1 : 0;
                        r3 += (kt < k3) ? 1 : 0;
                    }
                    if (sl + 64 < base && r2 < 32) KEYq[r2] = k2;
                    if (sl + 96 < base && r3 < 32) KEYq[r3] = k3;
                }
                if (sl      < base && r0 < 32) KEYq[r0] = k0;
                if (sl + 32 < base && r1 < 32) KEYq[r1] = k1;
                if (base < 32 && sl >= base) KEYq[sl] = ~0ull;   // pad -> NaN -> expand
                const unsigned long long kf = KEYq[sl];
                bd = __uint_as_float((unsigned)(kf >> 32));
                bi = (int)(unsigned)(kf & 0xffffffffull);
            } else {
                // overflow fallback: serial insertion over the box
                float fd = INF; int fi = 0x7FFFFFFF;
                for (int r = 0; r < nrows; ++r) {
                    const int s = __shfl(sv, r, 32), e = __shfl(ev, r, 32);
                    for (int j0 = s; j0 < e; j0 += 32) {
                        const int j = j0 + sl;
                        const bool valid = (j < e);
                        float2 p = make_float2(0.f, 0.f);
                        int vi0 = 0x7FFFFFFF;
                        if (valid) { p = PS[j]; vi0 = IS[j]; }
                        const float dx = q.x - p.x, dy = q.y - p.y;
                        const float d2 = __builtin_fmaf(dy, dy, __fmul_rn(dx, dx));
                        unsigned cm = (unsigned)(__ballot(valid && (d2 <= tau2b)) >> (half << 5));
                        const float ex = __fsqrt_rn(__fadd_rn(__fmul_rn(dx, dx),
                                                              __fmul_rn(dy, dy)));
                        while (cm) {
                            const int l = __builtin_ctz(cm); cm &= cm - 1;
                            const float v  = __shfl(ex, l, 32);
                            const int   vi = __shfl(vi0, l, 32);
                            const bool cl = (fd < v) || (fd == v && fi < vi);
                            const int pos = __popc((unsigned)(__ballot(cl) >> (half << 5)));
                            const float sd = __shfl_up(fd, 1, 32);
                            const int   si = __shfl_up(fi, 1, 32);
                            fd = (sl < pos) ? fd : ((sl == pos) ? v  : sd);
                            fi = (sl < pos) ? fi : ((sl == pos) ? vi : si);
                        }
                    }
                }
                bd = fd; bi = fi;
            }

            // exactness check vs unexamined region
            const float tau = __shfl(bd, 31, 32);      // NaN if < 32 candidates
            float g = INF;
            if (xlo > 0)        g = fminf(g, q.x - (float)xlo * h);
            if (xhi < GRID - 1) g = fminf(g, (float)(xhi + 1) * h - q.x);
            if (ylo > 0)        g = fminf(g, q.y - (float)ylo * h);
            if (yhi < GRID - 1) g = fminf(g, (float)(yhi + 1) * h - q.y);
            if (tau < g * (1.0f - 4e-6f)) break;       // NaN -> expand
            L += 2;
            if (L > GRID - 1) L = GRID - 1;            // full box => g = INF => done
        }
    }

    __builtin_amdgcn_sched_barrier(0);   // contain live ranges at phase boundary

    // ---- outputs 0 and 1: uiv_k and idx (as float) ----
    {
        const float2 pk = P[bi];
        float2 u;
        u.x = q.x - pk.x;
        u.y = q.y - pk.y;
        ((float2*)out_uiv)[(size_t)wid * KK + sl] = u;
        out_idx[(size_t)wid * KK + sl] = (float)bi;
    }

    __builtin_amdgcn_sched_barrier(0);

    // ---- T[e][i] = sum_k exp(-256*(r_k - mu_e)^2) * values_in[b, idx_k, i] ----
    // lane = (e-pair, i-quarter): 2 float4 loads per k (32B).
    // TLq written and read by this same half-wave only -> no barrier needed.
    {
        const int e2 = sl >> 2;                 // 0..7 -> e in {2*e2, 2*e2+1}
        const int iq = sl & 3;                  // i-block of 8
        const float mu0 = (float)(2 * e2)     * (1.0f / 15.0f);
        const float mu1 = (float)(2 * e2 + 1) * (1.0f / 15.0f);
        float4 A0a = make_float4(0.f, 0.f, 0.f, 0.f);
        float4 A0b = A0a, A1a = A0a, A1b = A0a;
#pragma unroll
        for (int k = 0; k < KK; ++k) {
            const float rk  = __shfl(bd, k, 32);
            const int   bik = __shfl(bi, k, 32);
            const float d0 = rk - mu0;
            const float d1 = rk - mu1;
            const float w0 = __expf(-256.0f * d0 * d0);
            const float w1 = __expf(-256.0f * d1 * d1);
            const float4* vr = (const float4*)(values_in + ((size_t)b * NN + bik) * CIN + iq * 8);
            const float4 va = vr[0], vb = vr[1];
            A0a.x += w0 * va.x; A0a.y += w0 * va.y; A0a.z += w0 * va.z; A0a.w += w0 * va.w;
            A0b.x += w0 * vb.x; A0b.y += w0 * vb.y; A0b.z += w0 * vb.z; A0b.w += w0 * vb.w;
            A1a.x += w1 * va.x; A1a.y += w1 * va.y; A1a.z += w1 * va.z; A1a.w += w1 * va.w;
            A1b.x += w1 * vb.x; A1b.y += w1 * vb.y; A1b.z += w1 * vb.z; A1b.w += w1 * vb.w;
        }
        float4* t0 = (float4*)(TLq + (2 * e2)     * 36 + iq * 8);
        float4* t1 = (float4*)(TLq + (2 * e2 + 1) * 36 + iq * 8);
        t0[0] = A0a; t0[1] = A0b;
        t1[0] = A1a; t1[1] = A1b;
    }

    __builtin_amdgcn_sched_barrier(0);

    // ---- out[o] = (1/K) * sum_{e,i} coeffT[e][o][i] * T[e][i] + bias[o] ----
    {
        const int o = sl;
        float s = 0.f;
#pragma unroll
        for (int e2 = 0; e2 < EE; ++e2) {
            const float4* crow = (const float4*)(coeffT + ((size_t)e2 * COUT + o) * CIN);
            const float4* trow = (const float4*)(TLq + e2 * 36);
#pragma unroll
            for (int i4 = 0; i4 < 8; ++i4) {
                const float4 c  = crow[i4];
                const float4 tv = trow[i4];
                s += c.x * tv.x + c.y * tv.y + c.z * tv.z + c.w * tv.w;
            }
        }
        out_val[(size_t)wid * COUT + o] = s * (1.0f / 32.0f) + bias[o];
    }
}

extern "C" void kernel_launch(void* const* d_in, const int* in_sizes, int n_in,
                              void* d_out, int out_size, void* d_ws, size_t ws_size,
                              hipStream_t stream) {
    const float* points_in  = (const float*)d_in[0];
    const float* values_in  = (const float*)d_in[1];
    const float* points_out = (const float*)d_in[2];
    const float* coeff      = (const float*)d_in[3];
    const float* bias       = (const float*)d_in[4];

    float* out     = (float*)d_out;
    float* out_uiv = out;                                        // B*M*K*2
    float* out_idx = out + (size_t)BB * MM * KK * 2;             // B*M*K
    float* out_val = out_idx + (size_t)BB * MM * KK;             // B*M*COUT

    char* ws = (char*)d_ws;
    float*  coeffT = (float*)(ws + OFS_COEFFT);
    int*    counts = (int*)  (ws + OFS_COUNTS);
    int*    cursor = (int*)  (ws + OFS_CURSOR);
    int*    strts  = (int*)  (ws + OFS_STARTS);
    float2* pts_s  = (float2*)(ws + OFS_PTSS);
    int*    idx_s  = (int*)  (ws + OFS_IDXS);

    hipLaunchKernelGGL(transpose_coeff, dim3(64), dim3(256), 0, stream, coeff, coeffT);
    hipLaunchKernelGGL(bin_zero, dim3(16), dim3(256), 0, stream, counts);
    hipLaunchKernelGGL(bin_count, dim3(64), dim3(256), 0, stream, points_in, counts);
    hipLaunchKernelGGL(bin_scan, dim3(1), dim3(1024), 0, stream, counts, strts);
    hipLaunchKernelGGL(bin_scatter, dim3(64), dim3(256), 0, stream,
                       points_in, strts, cursor, pts_s, idx_s);

    const int blocks = (BB * MM) / QPB;                          // 2048
    hipLaunchKernelGGL(conv_query, dim3(blocks), dim3(256), 0, stream,
                       pts_s, idx_s, strts, points_in, values_in, points_out,
                       coeffT, bias, out_uiv, out_idx, out_val);
}